// Round 3
// baseline (495.912 us; speedup 1.0000x reference)
//
#include <hip/hip_runtime.h>

#define BB 4
#define CC 256
#define NN 4096
#define CNT (CC*NN)

typedef float f32x4 __attribute__((ext_vector_type(4)));
typedef short bf16x8 __attribute__((ext_vector_type(8)));

__device__ inline ushort f2bf(float f) {
    union { float f; uint u; } v; v.f = f;
    uint r = v.u + 0x7fff + ((v.u >> 16) & 1);
    return (ushort)(r >> 16);
}

#define MFMA16(d, a, b) d = __builtin_amdgcn_mfma_f32_16x16x32_bf16(a, b, d, 0, 0, 0)

// ---------------- stats: deterministic two-stage sum/sumsq per batch ----------------
__global__ __launch_bounds__(256) void stats_part(const float* __restrict__ x,
                                                  float* __restrict__ part) {
    int b = blockIdx.y;
    const float* xb = x + b * CNT;
    float s = 0.f, q = 0.f;
    int base = (blockIdx.x * 256 + threadIdx.x) * 4;
    for (int i = base; i < CNT; i += 64 * 256 * 4) {
        f32x4 v = *(const f32x4*)(xb + i);
        s += (v.x + v.y) + (v.z + v.w);
        q += (v.x * v.x + v.y * v.y) + (v.z * v.z + v.w * v.w);
    }
    for (int off = 32; off; off >>= 1) {
        s += __shfl_down(s, off, 64);
        q += __shfl_down(q, off, 64);
    }
    __shared__ float red[8];
    int lane = threadIdx.x & 63, wv = threadIdx.x >> 6;
    if (!lane) { red[wv * 2] = s; red[wv * 2 + 1] = q; }
    __syncthreads();
    if (threadIdx.x == 0) {
        part[(b * 64 + blockIdx.x) * 2 + 0] = red[0] + red[2] + red[4] + red[6];
        part[(b * 64 + blockIdx.x) * 2 + 1] = red[1] + red[3] + red[5] + red[7];
    }
}

__global__ __launch_bounds__(256) void stats_final(const float* __restrict__ part,
                                                   float* __restrict__ stats) {
    int t = threadIdx.x;
    int b = t >> 6, lane = t & 63;
    float s = part[(b * 64 + lane) * 2 + 0];
    float q = part[(b * 64 + lane) * 2 + 1];
    for (int off = 32; off; off >>= 1) {
        s += __shfl_down(s, off, 64);
        q += __shfl_down(q, off, 64);
    }
    if (lane == 0) { stats[b * 2] = s; stats[b * 2 + 1] = q; }
}

// ---------------- norm + transpose: x[b][c][n] fp32 -> xn_t[b][n][c] bf16 ----------------
__global__ __launch_bounds__(256) void norm_t_kernel(
    const float* __restrict__ x, const float* __restrict__ gamma,
    const float* __restrict__ beta, const float* __restrict__ stats,
    ushort* __restrict__ xn_t)
{
    int b = blockIdx.z;
    float mean = stats[b * 2] * (1.0f / (float)CNT);
    float var = stats[b * 2 + 1] * (1.0f / (float)CNT) - mean * mean;
    float rinv = rsqrtf(var + 1e-5f);
    int n0 = blockIdx.x * 32, c0 = blockIdx.y * 32;
    __shared__ float tl[32][33];
    int tr = threadIdx.x >> 3;
    int tc4 = (threadIdx.x & 7) * 4;
    int c = c0 + tr;
    float gsc = gamma[c] * rinv;
    float bsc = beta[c] - mean * gsc;
    f32x4 v = *(const f32x4*)(x + ((b * CC + c) * NN + n0 + tc4));
    tl[tr][tc4 + 0] = v.x * gsc + bsc;
    tl[tr][tc4 + 1] = v.y * gsc + bsc;
    tl[tr][tc4 + 2] = v.z * gsc + bsc;
    tl[tr][tc4 + 3] = v.w * gsc + bsc;
    __syncthreads();
    int nr = threadIdx.x >> 3;
    int cg4 = (threadIdx.x & 7) * 4;
    ushort4 o;
    o.x = f2bf(tl[cg4 + 0][nr]);
    o.y = f2bf(tl[cg4 + 1][nr]);
    o.z = f2bf(tl[cg4 + 2][nr]);
    o.w = f2bf(tl[cg4 + 3][nr]);
    *(ushort4*)(xn_t + ((size_t)(b * NN + n0 + nr) * CC + c0 + cg4)) = o;
}

// ---------------- QKV GEMM: [768,256]x[256,4096] per batch, bf16 MFMA ----------------
// Q rows are PRE-SCALED by 2^-4 (= C^-0.5) so flash needs no scale.
__global__ __launch_bounds__(256) void qkv_kernel(
    const ushort* __restrict__ xn_t, const float* __restrict__ qkv_w,
    const float* __restrict__ qkv_b, ushort* __restrict__ q_t,
    ushort* __restrict__ k_t, ushort* __restrict__ v_g)
{
    int b = blockIdx.z;
    int d0 = blockIdx.x * 64;
    int i0 = blockIdx.y * 64;
    int t = threadIdx.x, w = t >> 6, l = t & 63, l15 = l & 15, g = l >> 4;
    __shared__ ushort b_lds[64 * 256];

    #pragma unroll
    for (int it = 0; it < 8; it++) {
        int cid = it * 256 + t;
        int rr = cid >> 5, cc = cid & 31;
        bf16x8 vv = *(const bf16x8*)(xn_t + ((size_t)(b * NN + i0 + rr) * CC + cc * 8));
        *(bf16x8*)(b_lds + rr * 256 + (cc ^ (rr & 7)) * 8) = vv;
    }
    bf16x8 af[8];
    int drow = d0 + w * 16 + l15;
    #pragma unroll
    for (int kk = 0; kk < 8; kk++) {
        const float* ap = qkv_w + drow * CC + kk * 32 + g * 8;
        f32x4 u0 = *(const f32x4*)ap;
        f32x4 u1 = *(const f32x4*)(ap + 4);
        bf16x8 a;
        a[0] = (short)f2bf(u0.x); a[1] = (short)f2bf(u0.y);
        a[2] = (short)f2bf(u0.z); a[3] = (short)f2bf(u0.w);
        a[4] = (short)f2bf(u1.x); a[5] = (short)f2bf(u1.y);
        a[6] = (short)f2bf(u1.z); a[7] = (short)f2bf(u1.w);
        af[kk] = a;
    }
    __syncthreads();

    f32x4 acc[4];
    #pragma unroll
    for (int it = 0; it < 4; it++) { f32x4 z = {0.f, 0.f, 0.f, 0.f}; acc[it] = z; }
    #pragma unroll
    for (int kk = 0; kk < 8; kk++) {
        int cc = kk * 4 + g;
        #pragma unroll
        for (int it = 0; it < 4; it++) {
            int il = it * 16 + l15;
            bf16x8 bf = *(const bf16x8*)(b_lds + il * 256 + (cc ^ (il & 7)) * 8);
            MFMA16(acc[it], af[kk], bf);
        }
    }
    int dbase = d0 + w * 16 + g * 4;
    f32x4 bias = *(const f32x4*)(qkv_b + dbase);
    float qs = (d0 < 256) ? 0.0625f : 1.0f;
    #pragma unroll
    for (int it = 0; it < 4; it++) {
        int i = i0 + it * 16 + l15;
        if (d0 < 512) {
            ushort4 o;
            o.x = f2bf((acc[it][0] + bias[0]) * qs);
            o.y = f2bf((acc[it][1] + bias[1]) * qs);
            o.z = f2bf((acc[it][2] + bias[2]) * qs);
            o.w = f2bf((acc[it][3] + bias[3]) * qs);
            ushort* dst = (d0 < 256) ? q_t : k_t;
            int dl = dbase - ((d0 < 256) ? 0 : 256);
            *(ushort4*)(dst + ((size_t)(b * NN + i) * CC + dl)) = o;
        } else {
            #pragma unroll
            for (int e = 0; e < 4; e++)
                v_g[(size_t)(b * CC + (dbase - 512 + e)) * NN + i] = f2bf(acc[it][e] + bias[e]);
        }
    }
}

// ---------------- flash attention, KV-split into gridDim.y segments ----------------
// PARTIAL: write fp32 partial O + (m,l) to ws; else write normalized bf16 out_t.
template <bool PARTIAL>
__global__ __launch_bounds__(256) void flash_kernel(
    const ushort* __restrict__ q_t, const ushort* __restrict__ k_t,
    const ushort* __restrict__ v_g, ushort* __restrict__ out_t,
    float* __restrict__ O_part, float* __restrict__ ml_part, int segn)
{
    int b = blockIdx.z;
    int seg = blockIdx.y;
    int i0 = blockIdx.x * 64;
    int jbase = seg * segn;
    int t = threadIdx.x;
    int w = t >> 6, l = t & 63, l15 = l & 15, g = l >> 4;

    __shared__ ushort k_lds[32 * 256];
    __shared__ ushort v_lds[256 * 32];
    __shared__ ushort p_lds[64 * 32];

    bf16x8 qf[8];
    size_t qrow = (size_t)(b * NN + i0 + w * 16 + l15) * CC + g * 8;
    #pragma unroll
    for (int kk = 0; kk < 8; kk++) qf[kk] = *(const bf16x8*)(q_t + qrow + kk * 32);

    f32x4 O[16];
    #pragma unroll
    for (int tc = 0; tc < 16; tc++) { f32x4 z = {0.f, 0.f, 0.f, 0.f}; O[tc] = z; }
    float m_r[4], l_r[4];
    #pragma unroll
    for (int e = 0; e < 4; e++) { m_r[e] = -1e30f; l_r[e] = 0.f; }

    const ushort* kb = k_t + (size_t)b * NN * CC;
    const ushort* vb = v_g + (size_t)b * CC * NN;

    bf16x8 kr[4], vr[4];
    #pragma unroll
    for (int it = 0; it < 4; it++) {
        int cid = it * 256 + t;
        kr[it] = *(const bf16x8*)(kb + (size_t)(jbase + (cid >> 5)) * CC + (cid & 31) * 8);
        vr[it] = *(const bf16x8*)(vb + (size_t)(cid >> 2) * NN + jbase + (cid & 3) * 8);
    }

    for (int jj = 0; jj < segn; jj += 32) {
        __syncthreads();
        #pragma unroll
        for (int it = 0; it < 4; it++) {
            int cid = it * 256 + t;
            int jr = cid >> 5, cck = cid & 31;
            *(bf16x8*)(k_lds + jr * 256 + (cck ^ (jr & 7)) * 8) = kr[it];
            int cr = cid >> 2, ccv = cid & 3;
            *(bf16x8*)(v_lds + cr * 32 + ((ccv ^ ((cr >> 1) & 3)) * 8)) = vr[it];
        }
        __syncthreads();

        if (jj + 32 < segn) {
            #pragma unroll
            for (int it = 0; it < 4; it++) {
                int cid = it * 256 + t;
                kr[it] = *(const bf16x8*)(kb + (size_t)(jbase + jj + 32 + (cid >> 5)) * CC + (cid & 31) * 8);
                vr[it] = *(const bf16x8*)(vb + (size_t)(cid >> 2) * NN + jbase + jj + 32 + (cid & 3) * 8);
            }
        }

        f32x4 s0 = {0.f, 0.f, 0.f, 0.f}, s1 = {0.f, 0.f, 0.f, 0.f};
        #pragma unroll
        for (int kk = 0; kk < 8; kk++) {
            int cc = kk * 4 + g;
            int j0l = l15, j1l = 16 + l15;
            bf16x8 b0 = *(const bf16x8*)(k_lds + j0l * 256 + (cc ^ (j0l & 7)) * 8);
            bf16x8 b1 = *(const bf16x8*)(k_lds + j1l * 256 + (cc ^ (j1l & 7)) * 8);
            MFMA16(s0, qf[kk], b0);
            MFMA16(s1, qf[kk], b1);
        }

        // online softmax with deferred-max (T13): rescale only if tile max exceeds m+8
        float pf0[4], pf1[4];
        #pragma unroll
        for (int e = 0; e < 4; e++) {
            float a0 = s0[e], a1 = s1[e];
            float mx = fmaxf(a0, a1);
            mx = fmaxf(mx, __shfl_xor(mx, 1, 64));
            mx = fmaxf(mx, __shfl_xor(mx, 2, 64));
            mx = fmaxf(mx, __shfl_xor(mx, 4, 64));
            mx = fmaxf(mx, __shfl_xor(mx, 8, 64));
            if (mx > m_r[e] + 8.0f) {   // rare after warm-up
                float fac = __expf(m_r[e] - mx);
                l_r[e] *= fac;
                #pragma unroll
                for (int tc = 0; tc < 16; tc++) O[tc][e] *= fac;
                m_r[e] = mx;
            }
            float p0 = __expf(a0 - m_r[e]), p1 = __expf(a1 - m_r[e]);
            float rs = p0 + p1;
            rs += __shfl_xor(rs, 1, 64);
            rs += __shfl_xor(rs, 2, 64);
            rs += __shfl_xor(rs, 4, 64);
            rs += __shfl_xor(rs, 8, 64);
            l_r[e] += rs;
            pf0[e] = p0; pf1[e] = p1;
        }

        #pragma unroll
        for (int e = 0; e < 4; e++) {
            int ir = w * 16 + g * 4 + e;
            int ja = l15, jb = 16 + l15;
            p_lds[ir * 32 + (((ja >> 3) ^ ((ir >> 1) & 3)) * 8) + (ja & 7)] = f2bf(pf0[e]);
            p_lds[ir * 32 + (((jb >> 3) ^ ((ir >> 1) & 3)) * 8) + (jb & 7)] = f2bf(pf1[e]);
        }
        int ip = w * 16 + l15;
        bf16x8 pa = *(const bf16x8*)(p_lds + ip * 32 + ((g ^ ((ip >> 1) & 3)) * 8));

        #pragma unroll
        for (int tc = 0; tc < 16; tc++) {
            int c = tc * 16 + l15;
            bf16x8 vf = *(const bf16x8*)(v_lds + c * 32 + ((g ^ ((c >> 1) & 3)) * 8));
            MFMA16(O[tc], pa, vf);
        }
    }

    if (PARTIAL) {
        size_t obase = ((size_t)(seg * BB + b) * NN);
        #pragma unroll
        for (int e = 0; e < 4; e++) {
            int ir = i0 + w * 16 + g * 4 + e;
            float* orow = O_part + (obase + ir) * CC;
            #pragma unroll
            for (int tc = 0; tc < 16; tc++)
                orow[tc * 16 + l15] = O[tc][e];
            if (l15 == 0) {
                ml_part[(obase + ir) * 2 + 0] = m_r[e];
                ml_part[(obase + ir) * 2 + 1] = l_r[e];
            }
        }
    } else {
        #pragma unroll
        for (int e = 0; e < 4; e++) {
            float inv = 1.0f / fmaxf(l_r[e], 1e-20f);
            int ir = i0 + w * 16 + g * 4 + e;
            #pragma unroll
            for (int tc = 0; tc < 16; tc++)
                out_t[(size_t)(b * NN + ir) * CC + tc * 16 + l15] = f2bf(O[tc][e] * inv);
        }
    }
}

// ---------------- merge partial segments -> out_t bf16 ----------------
__global__ __launch_bounds__(256) void merge_kernel(
    const float* __restrict__ O_part, const float* __restrict__ ml_part,
    ushort* __restrict__ out_t, int S)
{
    int b = blockIdx.y;
    int t = threadIdx.x;
    int i = blockIdx.x * 64 + (t >> 2);
    int c0 = (t & 3) * 64;

    float w_s[4];
    float mstar = -1e30f;
    for (int s = 0; s < S; s++)
        mstar = fmaxf(mstar, ml_part[((size_t)(s * BB + b) * NN + i) * 2 + 0]);
    float lsum = 0.f;
    for (int s = 0; s < S; s++) {
        size_t mo = ((size_t)(s * BB + b) * NN + i) * 2;
        float wv = __expf(ml_part[mo] - mstar);
        lsum += ml_part[mo + 1] * wv;
        w_s[s] = wv;
    }
    float inv = 1.0f / fmaxf(lsum, 1e-20f);

    #pragma unroll 4
    for (int k = 0; k < 16; k++) {
        f32x4 acc = {0.f, 0.f, 0.f, 0.f};
        for (int s = 0; s < S; s++) {
            const float* op = O_part + ((size_t)(s * BB + b) * NN + i) * CC + c0 + k * 4;
            f32x4 v = *(const f32x4*)op;
            acc.x += v.x * w_s[s];
            acc.y += v.y * w_s[s];
            acc.z += v.z * w_s[s];
            acc.w += v.w * w_s[s];
        }
        ushort4 o;
        o.x = f2bf(acc.x * inv);
        o.y = f2bf(acc.y * inv);
        o.z = f2bf(acc.z * inv);
        o.w = f2bf(acc.w * inv);
        *(ushort4*)(out_t + (size_t)(b * NN + i) * CC + c0 + k * 4) = o;
    }
}

// ---------------- proj GEMM + bias + residual ----------------
__global__ __launch_bounds__(256) void proj_kernel(
    const ushort* __restrict__ out_t, const float* __restrict__ proj_w,
    const float* __restrict__ proj_b, const float* __restrict__ x,
    float* __restrict__ out)
{
    int b = blockIdx.z;
    int d0 = blockIdx.x * 64;
    int i0 = blockIdx.y * 256;
    int t = threadIdx.x, w = t >> 6, l = t & 63, l15 = l & 15, g = l >> 4;
    __shared__ ushort a_lds[64 * 256];

    #pragma unroll
    for (int it = 0; it < 8; it++) {
        int cid = it * 256 + t;
        int dd = cid >> 5, cc = cid & 31;
        const float* ap = proj_w + (d0 + dd) * CC + cc * 8;
        f32x4 u0 = *(const f32x4*)ap;
        f32x4 u1 = *(const f32x4*)(ap + 4);
        bf16x8 a;
        a[0] = (short)f2bf(u0.x); a[1] = (short)f2bf(u0.y);
        a[2] = (short)f2bf(u0.z); a[3] = (short)f2bf(u0.w);
        a[4] = (short)f2bf(u1.x); a[5] = (short)f2bf(u1.y);
        a[6] = (short)f2bf(u1.z); a[7] = (short)f2bf(u1.w);
        *(bf16x8*)(a_lds + dd * 256 + (cc ^ (dd & 7)) * 8) = a;
    }
    __syncthreads();

    f32x4 acc[16];
    #pragma unroll
    for (int it = 0; it < 16; it++) { f32x4 z = {0.f, 0.f, 0.f, 0.f}; acc[it] = z; }
    int dl = w * 16 + l15;
    #pragma unroll
    for (int kk = 0; kk < 8; kk++) {
        int cc = kk * 4 + g;
        bf16x8 af = *(const bf16x8*)(a_lds + dl * 256 + (cc ^ (dl & 7)) * 8);
        #pragma unroll
        for (int it = 0; it < 16; it++) {
            bf16x8 bfr = *(const bf16x8*)(out_t + (size_t)(b * NN + i0 + it * 16 + l15) * CC + kk * 32 + g * 8);
            MFMA16(acc[it], af, bfr);
        }
    }
    int dbase = d0 + w * 16 + g * 4;
    f32x4 pb = *(const f32x4*)(proj_b + dbase);
    #pragma unroll
    for (int it = 0; it < 16; it++) {
        int i = i0 + it * 16 + l15;
        #pragma unroll
        for (int e = 0; e < 4; e++) {
            int off = (b * CC + dbase + e) * NN + i;
            out[off] = acc[it][e] + pb[e] + x[off];
        }
    }
}

extern "C" void kernel_launch(void* const* d_in, const int* in_sizes, int n_in,
                              void* d_out, int out_size, void* d_ws, size_t ws_size,
                              hipStream_t stream) {
    const float* x      = (const float*)d_in[0];
    const float* gamma  = (const float*)d_in[1];
    const float* beta   = (const float*)d_in[2];
    const float* qkv_w  = (const float*)d_in[3];
    const float* qkv_b  = (const float*)d_in[4];
    const float* proj_w = (const float*)d_in[5];
    const float* proj_b = (const float*)d_in[6];
    float* out = (float*)d_out;

    char* ws = (char*)d_ws;
    float* part   = (float*)ws;
    float* stats  = (float*)(ws + 2048);
    ushort* xn_t  = (ushort*)(ws + 4096);
    ushort* q_t   = (ushort*)(ws + 4096 + 1ull * 8388608);
    ushort* k_t   = (ushort*)(ws + 4096 + 2ull * 8388608);
    ushort* v_g   = (ushort*)(ws + 4096 + 3ull * 8388608);
    ushort* out_t = xn_t;

    size_t mlbase = 4096 + 4ull * 8388608;            // 32 MB + 4 KB
    float* ml_part = (float*)(ws + mlbase);           // up to 512 KB
    size_t obase  = mlbase + 1048576;
    float* O_part = (float*)(ws + obase);             // S * 16 MB

    int S = 0;
    if (ws_size >= obase + 4ull * 16777216) S = 4;
    else if (ws_size >= obase + 2ull * 16777216) S = 2;
    else if (ws_size >= obase + 1ull * 16777216) S = 1;

    stats_part<<<dim3(64, 4), 256, 0, stream>>>(x, part);
    stats_final<<<1, 256, 0, stream>>>(part, stats);
    norm_t_kernel<<<dim3(128, 8, 4), 256, 0, stream>>>(x, gamma, beta, stats, xn_t);
    qkv_kernel<<<dim3(12, 64, 4), 256, 0, stream>>>(xn_t, qkv_w, qkv_b, q_t, k_t, v_g);
    if (S > 0) {
        flash_kernel<true><<<dim3(64, S, 4), 256, 0, stream>>>(
            q_t, k_t, v_g, out_t, O_part, ml_part, NN / S);
        merge_kernel<<<dim3(64, 4), 256, 0, stream>>>(O_part, ml_part, out_t, S);
    } else {
        flash_kernel<false><<<dim3(64, 1, 4), 256, 0, stream>>>(
            q_t, k_t, v_g, out_t, nullptr, nullptr, NN);
    }
    proj_kernel<<<dim3(4, 16, 4), 256, 0, stream>>>(out_t, proj_w, proj_b, x, out);
}

// Round 4
// 227.136 us; speedup vs baseline: 2.1833x; 2.1833x over previous
//
#include <hip/hip_runtime.h>

#define BB 4
#define CC 256
#define NN 4096
#define CNT (CC*NN)

typedef float f32x4 __attribute__((ext_vector_type(4)));
typedef short bf16x8 __attribute__((ext_vector_type(8)));

__device__ inline ushort f2bf(float f) {
    union { float f; uint u; } v; v.f = f;
    uint r = v.u + 0x7fff + ((v.u >> 16) & 1);
    return (ushort)(r >> 16);
}

#define MFMA16(d, a, b) d = __builtin_amdgcn_mfma_f32_16x16x32_bf16(a, b, d, 0, 0, 0)

// ---------------- stats: deterministic two-stage sum/sumsq per batch ----------------
__global__ __launch_bounds__(256) void stats_part(const float* __restrict__ x,
                                                  float* __restrict__ part) {
    int b = blockIdx.y;
    const float* xb = x + b * CNT;
    float s = 0.f, q = 0.f;
    int base = (blockIdx.x * 256 + threadIdx.x) * 4;
    for (int i = base; i < CNT; i += 64 * 256 * 4) {
        f32x4 v = *(const f32x4*)(xb + i);
        s += (v.x + v.y) + (v.z + v.w);
        q += (v.x * v.x + v.y * v.y) + (v.z * v.z + v.w * v.w);
    }
    for (int off = 32; off; off >>= 1) {
        s += __shfl_down(s, off, 64);
        q += __shfl_down(q, off, 64);
    }
    __shared__ float red[8];
    int lane = threadIdx.x & 63, wv = threadIdx.x >> 6;
    if (!lane) { red[wv * 2] = s; red[wv * 2 + 1] = q; }
    __syncthreads();
    if (threadIdx.x == 0) {
        part[(b * 64 + blockIdx.x) * 2 + 0] = red[0] + red[2] + red[4] + red[6];
        part[(b * 64 + blockIdx.x) * 2 + 1] = red[1] + red[3] + red[5] + red[7];
    }
}

__global__ __launch_bounds__(256) void stats_final(const float* __restrict__ part,
                                                   float* __restrict__ stats) {
    int t = threadIdx.x;
    int b = t >> 6, lane = t & 63;
    float s = part[(b * 64 + lane) * 2 + 0];
    float q = part[(b * 64 + lane) * 2 + 1];
    for (int off = 32; off; off >>= 1) {
        s += __shfl_down(s, off, 64);
        q += __shfl_down(q, off, 64);
    }
    if (lane == 0) { stats[b * 2] = s; stats[b * 2 + 1] = q; }
}

// ---------------- norm + transpose: x[b][c][n] fp32 -> xn_t[b][n][c] bf16 ----------------
__global__ __launch_bounds__(256) void norm_t_kernel(
    const float* __restrict__ x, const float* __restrict__ gamma,
    const float* __restrict__ beta, const float* __restrict__ stats,
    ushort* __restrict__ xn_t)
{
    int b = blockIdx.z;
    float mean = stats[b * 2] * (1.0f / (float)CNT);
    float var = stats[b * 2 + 1] * (1.0f / (float)CNT) - mean * mean;
    float rinv = rsqrtf(var + 1e-5f);
    int n0 = blockIdx.x * 32, c0 = blockIdx.y * 32;
    __shared__ float tl[32][33];
    int tr = threadIdx.x >> 3;
    int tc4 = (threadIdx.x & 7) * 4;
    int c = c0 + tr;
    float gsc = gamma[c] * rinv;
    float bsc = beta[c] - mean * gsc;
    f32x4 v = *(const f32x4*)(x + ((b * CC + c) * NN + n0 + tc4));
    tl[tr][tc4 + 0] = v.x * gsc + bsc;
    tl[tr][tc4 + 1] = v.y * gsc + bsc;
    tl[tr][tc4 + 2] = v.z * gsc + bsc;
    tl[tr][tc4 + 3] = v.w * gsc + bsc;
    __syncthreads();
    int nr = threadIdx.x >> 3;
    int cg4 = (threadIdx.x & 7) * 4;
    ushort4 o;
    o.x = f2bf(tl[cg4 + 0][nr]);
    o.y = f2bf(tl[cg4 + 1][nr]);
    o.z = f2bf(tl[cg4 + 2][nr]);
    o.w = f2bf(tl[cg4 + 3][nr]);
    *(ushort4*)(xn_t + ((size_t)(b * NN + n0 + nr) * CC + c0 + cg4)) = o;
}

// ---------------- QKV GEMM: [768,256]x[256,4096] per batch, bf16 MFMA ----------------
// Q rows are PRE-SCALED by 2^-4 (= C^-0.5) so flash needs no scale.
__global__ __launch_bounds__(256) void qkv_kernel(
    const ushort* __restrict__ xn_t, const float* __restrict__ qkv_w,
    const float* __restrict__ qkv_b, ushort* __restrict__ q_t,
    ushort* __restrict__ k_t, ushort* __restrict__ v_g)
{
    int b = blockIdx.z;
    int d0 = blockIdx.x * 64;
    int i0 = blockIdx.y * 64;
    int t = threadIdx.x, w = t >> 6, l = t & 63, l15 = l & 15, g = l >> 4;
    __shared__ ushort b_lds[64 * 256];

    #pragma unroll
    for (int it = 0; it < 8; it++) {
        int cid = it * 256 + t;
        int rr = cid >> 5, cc = cid & 31;
        bf16x8 vv = *(const bf16x8*)(xn_t + ((size_t)(b * NN + i0 + rr) * CC + cc * 8));
        *(bf16x8*)(b_lds + rr * 256 + (cc ^ (rr & 7)) * 8) = vv;
    }
    bf16x8 af[8];
    int drow = d0 + w * 16 + l15;
    #pragma unroll
    for (int kk = 0; kk < 8; kk++) {
        const float* ap = qkv_w + drow * CC + kk * 32 + g * 8;
        f32x4 u0 = *(const f32x4*)ap;
        f32x4 u1 = *(const f32x4*)(ap + 4);
        bf16x8 a;
        a[0] = (short)f2bf(u0.x); a[1] = (short)f2bf(u0.y);
        a[2] = (short)f2bf(u0.z); a[3] = (short)f2bf(u0.w);
        a[4] = (short)f2bf(u1.x); a[5] = (short)f2bf(u1.y);
        a[6] = (short)f2bf(u1.z); a[7] = (short)f2bf(u1.w);
        af[kk] = a;
    }
    __syncthreads();

    f32x4 acc[4];
    #pragma unroll
    for (int it = 0; it < 4; it++) { f32x4 z = {0.f, 0.f, 0.f, 0.f}; acc[it] = z; }
    #pragma unroll
    for (int kk = 0; kk < 8; kk++) {
        int cc = kk * 4 + g;
        #pragma unroll
        for (int it = 0; it < 4; it++) {
            int il = it * 16 + l15;
            bf16x8 bf = *(const bf16x8*)(b_lds + il * 256 + (cc ^ (il & 7)) * 8);
            MFMA16(acc[it], af[kk], bf);
        }
    }
    int dbase = d0 + w * 16 + g * 4;
    f32x4 bias = *(const f32x4*)(qkv_b + dbase);
    float qs = (d0 < 256) ? 0.0625f : 1.0f;
    #pragma unroll
    for (int it = 0; it < 4; it++) {
        int i = i0 + it * 16 + l15;
        if (d0 < 512) {
            ushort4 o;
            o.x = f2bf((acc[it][0] + bias[0]) * qs);
            o.y = f2bf((acc[it][1] + bias[1]) * qs);
            o.z = f2bf((acc[it][2] + bias[2]) * qs);
            o.w = f2bf((acc[it][3] + bias[3]) * qs);
            ushort* dst = (d0 < 256) ? q_t : k_t;
            int dl = dbase - ((d0 < 256) ? 0 : 256);
            *(ushort4*)(dst + ((size_t)(b * NN + i) * CC + dl)) = o;
        } else {
            #pragma unroll
            for (int e = 0; e < 4; e++)
                v_g[(size_t)(b * CC + (dbase - 512 + e)) * NN + i] = f2bf(acc[it][e] + bias[e]);
        }
    }
}

// ---------------- flash attention: 8-wave blocks (128 Q rows), KV-split ----------------
// 2 waves/SIMD co-resident by construction. Common-path softmax has NO cross-lane ops:
// per-lane threshold check + __any; l-sum reduce deferred to epilogue.
template <bool PARTIAL>
__global__ __launch_bounds__(512, 2) void flash_kernel(
    const ushort* __restrict__ q_t, const ushort* __restrict__ k_t,
    const ushort* __restrict__ v_g, ushort* __restrict__ out_t,
    float* __restrict__ O_part, float* __restrict__ ml_part, int segn)
{
    int b = blockIdx.z;
    int seg = blockIdx.y;
    int i0 = blockIdx.x * 128;
    int jbase = seg * segn;
    int t = threadIdx.x;
    int w = t >> 6, l = t & 63, l15 = l & 15, g = l >> 4;

    __shared__ ushort k_lds[32 * 256];   // [j][c], chunk-swizzled
    __shared__ ushort v_lds[256 * 32];   // [c][j], chunk-swizzled
    __shared__ ushort p_lds[128 * 32];   // [i][j], chunk-swizzled

    bf16x8 qf[8];
    size_t qrow = (size_t)(b * NN + i0 + w * 16 + l15) * CC + g * 8;
    #pragma unroll
    for (int kk = 0; kk < 8; kk++) qf[kk] = *(const bf16x8*)(q_t + qrow + kk * 32);

    f32x4 O[16];
    #pragma unroll
    for (int tc = 0; tc < 16; tc++) { f32x4 z = {0.f, 0.f, 0.f, 0.f}; O[tc] = z; }
    float m_r[4], l_r[4];
    #pragma unroll
    for (int e = 0; e < 4; e++) { m_r[e] = -1e30f; l_r[e] = 0.f; }

    const ushort* kb = k_t + (size_t)b * NN * CC;
    const ushort* vb = v_g + (size_t)b * CC * NN;

    bf16x8 kr[2], vr[2];
    #pragma unroll
    for (int it = 0; it < 2; it++) {
        int cid = it * 512 + t;
        kr[it] = *(const bf16x8*)(kb + (size_t)(jbase + (cid >> 5)) * CC + (cid & 31) * 8);
        vr[it] = *(const bf16x8*)(vb + (size_t)(cid >> 2) * NN + jbase + (cid & 3) * 8);
    }

    for (int jj = 0; jj < segn; jj += 32) {
        __syncthreads();
        #pragma unroll
        for (int it = 0; it < 2; it++) {
            int cid = it * 512 + t;
            int jr = cid >> 5, cck = cid & 31;
            *(bf16x8*)(k_lds + jr * 256 + (cck ^ (jr & 7)) * 8) = kr[it];
            int cr = cid >> 2, ccv = cid & 3;
            *(bf16x8*)(v_lds + cr * 32 + ((ccv ^ ((cr >> 1) & 3)) * 8)) = vr[it];
        }
        __syncthreads();

        if (jj + 32 < segn) {
            #pragma unroll
            for (int it = 0; it < 2; it++) {
                int cid = it * 512 + t;
                kr[it] = *(const bf16x8*)(kb + (size_t)(jbase + jj + 32 + (cid >> 5)) * CC + (cid & 31) * 8);
                vr[it] = *(const bf16x8*)(vb + (size_t)(cid >> 2) * NN + jbase + jj + 32 + (cid & 3) * 8);
            }
        }

        f32x4 s0 = {0.f, 0.f, 0.f, 0.f}, s1 = {0.f, 0.f, 0.f, 0.f};
        #pragma unroll
        for (int kk = 0; kk < 8; kk++) {
            int cc = kk * 4 + g;
            int j0l = l15, j1l = 16 + l15;
            bf16x8 b0 = *(const bf16x8*)(k_lds + j0l * 256 + (cc ^ (j0l & 7)) * 8);
            bf16x8 b1 = *(const bf16x8*)(k_lds + j1l * 256 + (cc ^ (j1l & 7)) * 8);
            MFMA16(s0, qf[kk], b0);
            MFMA16(s1, qf[kk], b1);
        }

        // softmax, common path cross-lane-free (deferred max + deferred l-reduce)
        float mxl[4];
        bool need = false;
        #pragma unroll
        for (int e = 0; e < 4; e++) {
            mxl[e] = fmaxf(s0[e], s1[e]);
            need = need || (mxl[e] > m_r[e] + 8.0f);
        }
        if (__any(need)) {
            #pragma unroll
            for (int e = 0; e < 4; e++) {
                float mx = mxl[e];
                mx = fmaxf(mx, __shfl_xor(mx, 1, 64));
                mx = fmaxf(mx, __shfl_xor(mx, 2, 64));
                mx = fmaxf(mx, __shfl_xor(mx, 4, 64));
                mx = fmaxf(mx, __shfl_xor(mx, 8, 64));
                if (mx > m_r[e]) {
                    float fac = __expf(m_r[e] - mx);
                    l_r[e] *= fac;
                    #pragma unroll
                    for (int tc = 0; tc < 16; tc++) O[tc][e] *= fac;
                    m_r[e] = mx;
                }
            }
        }
        float pf0[4], pf1[4];
        #pragma unroll
        for (int e = 0; e < 4; e++) {
            float p0 = __expf(s0[e] - m_r[e]);
            float p1 = __expf(s1[e] - m_r[e]);
            l_r[e] += p0 + p1;          // lane-local partial; reduced at end
            pf0[e] = p0; pf1[e] = p1;
        }

        #pragma unroll
        for (int e = 0; e < 4; e++) {
            int ir = w * 16 + g * 4 + e;
            int ja = l15, jb = 16 + l15;
            p_lds[ir * 32 + (((ja >> 3) ^ ((ir >> 1) & 3)) * 8) + (ja & 7)] = f2bf(pf0[e]);
            p_lds[ir * 32 + (((jb >> 3) ^ ((ir >> 1) & 3)) * 8) + (jb & 7)] = f2bf(pf1[e]);
        }
        int ip = w * 16 + l15;
        bf16x8 pa = *(const bf16x8*)(p_lds + ip * 32 + ((g ^ ((ip >> 1) & 3)) * 8));

        #pragma unroll
        for (int tc = 0; tc < 16; tc++) {
            int c = tc * 16 + l15;
            bf16x8 vf = *(const bf16x8*)(v_lds + c * 32 + ((g ^ ((c >> 1) & 3)) * 8));
            MFMA16(O[tc], pa, vf);
        }
    }

    // epilogue: reduce deferred l across the 16-lane group
    #pragma unroll
    for (int e = 0; e < 4; e++) {
        float rs = l_r[e];
        rs += __shfl_xor(rs, 1, 64);
        rs += __shfl_xor(rs, 2, 64);
        rs += __shfl_xor(rs, 4, 64);
        rs += __shfl_xor(rs, 8, 64);
        l_r[e] = rs;
    }

    if (PARTIAL) {
        size_t obase = ((size_t)(seg * BB + b) * NN);
        #pragma unroll
        for (int e = 0; e < 4; e++) {
            int ir = i0 + w * 16 + g * 4 + e;
            float* orow = O_part + (obase + ir) * CC;
            #pragma unroll
            for (int tc = 0; tc < 16; tc++)
                orow[tc * 16 + l15] = O[tc][e];
            if (l15 == 0) {
                ml_part[(obase + ir) * 2 + 0] = m_r[e];
                ml_part[(obase + ir) * 2 + 1] = l_r[e];
            }
        }
    } else {
        #pragma unroll
        for (int e = 0; e < 4; e++) {
            float inv = 1.0f / fmaxf(l_r[e], 1e-20f);
            int ir = i0 + w * 16 + g * 4 + e;
            #pragma unroll
            for (int tc = 0; tc < 16; tc++)
                out_t[(size_t)(b * NN + ir) * CC + tc * 16 + l15] = f2bf(O[tc][e] * inv);
        }
    }
}

// ---------------- merge partial segments -> out_t bf16 ----------------
__global__ __launch_bounds__(256) void merge_kernel(
    const float* __restrict__ O_part, const float* __restrict__ ml_part,
    ushort* __restrict__ out_t, int S)
{
    int b = blockIdx.y;
    int t = threadIdx.x;
    int i = blockIdx.x * 64 + (t >> 2);
    int c0 = (t & 3) * 64;

    float w_s[4];
    float mstar = -1e30f;
    for (int s = 0; s < S; s++)
        mstar = fmaxf(mstar, ml_part[((size_t)(s * BB + b) * NN + i) * 2 + 0]);
    float lsum = 0.f;
    for (int s = 0; s < S; s++) {
        size_t mo = ((size_t)(s * BB + b) * NN + i) * 2;
        float wv = __expf(ml_part[mo] - mstar);
        lsum += ml_part[mo + 1] * wv;
        w_s[s] = wv;
    }
    float inv = 1.0f / fmaxf(lsum, 1e-20f);

    #pragma unroll 4
    for (int k = 0; k < 16; k++) {
        f32x4 acc = {0.f, 0.f, 0.f, 0.f};
        for (int s = 0; s < S; s++) {
            const float* op = O_part + ((size_t)(s * BB + b) * NN + i) * CC + c0 + k * 4;
            f32x4 v = *(const f32x4*)op;
            acc.x += v.x * w_s[s];
            acc.y += v.y * w_s[s];
            acc.z += v.z * w_s[s];
            acc.w += v.w * w_s[s];
        }
        ushort4 o;
        o.x = f2bf(acc.x * inv);
        o.y = f2bf(acc.y * inv);
        o.z = f2bf(acc.z * inv);
        o.w = f2bf(acc.w * inv);
        *(ushort4*)(out_t + (size_t)(b * NN + i) * CC + c0 + k * 4) = o;
    }
}

// ---------------- proj GEMM + bias + residual ----------------
__global__ __launch_bounds__(256) void proj_kernel(
    const ushort* __restrict__ out_t, const float* __restrict__ proj_w,
    const float* __restrict__ proj_b, const float* __restrict__ x,
    float* __restrict__ out)
{
    int b = blockIdx.z;
    int d0 = blockIdx.x * 64;
    int i0 = blockIdx.y * 256;
    int t = threadIdx.x, w = t >> 6, l = t & 63, l15 = l & 15, g = l >> 4;
    __shared__ ushort a_lds[64 * 256];

    #pragma unroll
    for (int it = 0; it < 8; it++) {
        int cid = it * 256 + t;
        int dd = cid >> 5, cc = cid & 31;
        const float* ap = proj_w + (d0 + dd) * CC + cc * 8;
        f32x4 u0 = *(const f32x4*)ap;
        f32x4 u1 = *(const f32x4*)(ap + 4);
        bf16x8 a;
        a[0] = (short)f2bf(u0.x); a[1] = (short)f2bf(u0.y);
        a[2] = (short)f2bf(u0.z); a[3] = (short)f2bf(u0.w);
        a[4] = (short)f2bf(u1.x); a[5] = (short)f2bf(u1.y);
        a[6] = (short)f2bf(u1.z); a[7] = (short)f2bf(u1.w);
        *(bf16x8*)(a_lds + dd * 256 + (cc ^ (dd & 7)) * 8) = a;
    }
    __syncthreads();

    f32x4 acc[16];
    #pragma unroll
    for (int it = 0; it < 16; it++) { f32x4 z = {0.f, 0.f, 0.f, 0.f}; acc[it] = z; }
    int dl = w * 16 + l15;
    #pragma unroll
    for (int kk = 0; kk < 8; kk++) {
        int cc = kk * 4 + g;
        bf16x8 af = *(const bf16x8*)(a_lds + dl * 256 + (cc ^ (dl & 7)) * 8);
        #pragma unroll
        for (int it = 0; it < 16; it++) {
            bf16x8 bfr = *(const bf16x8*)(out_t + (size_t)(b * NN + i0 + it * 16 + l15) * CC + kk * 32 + g * 8);
            MFMA16(acc[it], af, bfr);
        }
    }
    int dbase = d0 + w * 16 + g * 4;
    f32x4 pb = *(const f32x4*)(proj_b + dbase);
    #pragma unroll
    for (int it = 0; it < 16; it++) {
        int i = i0 + it * 16 + l15;
        #pragma unroll
        for (int e = 0; e < 4; e++) {
            int off = (b * CC + dbase + e) * NN + i;
            out[off] = acc[it][e] + pb[e] + x[off];
        }
    }
}

extern "C" void kernel_launch(void* const* d_in, const int* in_sizes, int n_in,
                              void* d_out, int out_size, void* d_ws, size_t ws_size,
                              hipStream_t stream) {
    const float* x      = (const float*)d_in[0];
    const float* gamma  = (const float*)d_in[1];
    const float* beta   = (const float*)d_in[2];
    const float* qkv_w  = (const float*)d_in[3];
    const float* qkv_b  = (const float*)d_in[4];
    const float* proj_w = (const float*)d_in[5];
    const float* proj_b = (const float*)d_in[6];
    float* out = (float*)d_out;

    char* ws = (char*)d_ws;
    float* part   = (float*)ws;
    float* stats  = (float*)(ws + 2048);
    ushort* xn_t  = (ushort*)(ws + 4096);
    ushort* q_t   = (ushort*)(ws + 4096 + 1ull * 8388608);
    ushort* k_t   = (ushort*)(ws + 4096 + 2ull * 8388608);
    ushort* v_g   = (ushort*)(ws + 4096 + 3ull * 8388608);
    ushort* out_t = xn_t;

    size_t mlbase = 4096 + 4ull * 8388608;            // 32 MB + 4 KB
    float* ml_part = (float*)(ws + mlbase);           // up to 512 KB
    size_t obase  = mlbase + 1048576;
    float* O_part = (float*)(ws + obase);             // S * 16 MB

    int S = 0;
    if (ws_size >= obase + 2ull * 16777216) S = 2;    // 8-wave blocks: 32 i-blocks * S * 4 = 256

    stats_part<<<dim3(64, 4), 256, 0, stream>>>(x, part);
    stats_final<<<1, 256, 0, stream>>>(part, stats);
    norm_t_kernel<<<dim3(128, 8, 4), 256, 0, stream>>>(x, gamma, beta, stats, xn_t);
    qkv_kernel<<<dim3(12, 64, 4), 256, 0, stream>>>(xn_t, qkv_w, qkv_b, q_t, k_t, v_g);
    if (S > 0) {
        flash_kernel<true><<<dim3(32, S, 4), 512, 0, stream>>>(
            q_t, k_t, v_g, out_t, O_part, ml_part, NN / S);
        merge_kernel<<<dim3(64, 4), 256, 0, stream>>>(O_part, ml_part, out_t, S);
    } else {
        flash_kernel<false><<<dim3(32, 1, 4), 512, 0, stream>>>(
            q_t, k_t, v_g, out_t, nullptr, nullptr, NN);
    }
    proj_kernel<<<dim3(4, 16, 4), 256, 0, stream>>>(out_t, proj_w, proj_b, x, out);
}

// Round 5
// 225.101 us; speedup vs baseline: 2.2031x; 1.0090x over previous
//
#include <hip/hip_runtime.h>

#define BB 4
#define CC 256
#define NN 4096
#define CNT (CC*NN)

typedef float f32x4 __attribute__((ext_vector_type(4)));
typedef short bf16x8 __attribute__((ext_vector_type(8)));

__device__ inline ushort f2bf(float f) {
    union { float f; uint u; } v; v.f = f;
    uint r = v.u + 0x7fff + ((v.u >> 16) & 1);
    return (ushort)(r >> 16);
}

#define MFMA16(d, a, b) d = __builtin_amdgcn_mfma_f32_16x16x32_bf16(a, b, d, 0, 0, 0)

// ---------------- stats: deterministic two-stage sum/sumsq per batch ----------------
__global__ __launch_bounds__(256) void stats_part(const float* __restrict__ x,
                                                  float* __restrict__ part) {
    int b = blockIdx.y;
    const float* xb = x + b * CNT;
    float s = 0.f, q = 0.f;
    int base = (blockIdx.x * 256 + threadIdx.x) * 4;
    for (int i = base; i < CNT; i += 64 * 256 * 4) {
        f32x4 v = *(const f32x4*)(xb + i);
        s += (v.x + v.y) + (v.z + v.w);
        q += (v.x * v.x + v.y * v.y) + (v.z * v.z + v.w * v.w);
    }
    for (int off = 32; off; off >>= 1) {
        s += __shfl_down(s, off, 64);
        q += __shfl_down(q, off, 64);
    }
    __shared__ float red[8];
    int lane = threadIdx.x & 63, wv = threadIdx.x >> 6;
    if (!lane) { red[wv * 2] = s; red[wv * 2 + 1] = q; }
    __syncthreads();
    if (threadIdx.x == 0) {
        part[(b * 64 + blockIdx.x) * 2 + 0] = red[0] + red[2] + red[4] + red[6];
        part[(b * 64 + blockIdx.x) * 2 + 1] = red[1] + red[3] + red[5] + red[7];
    }
}

__global__ __launch_bounds__(256) void stats_final(const float* __restrict__ part,
                                                   float* __restrict__ stats) {
    int t = threadIdx.x;
    int b = t >> 6, lane = t & 63;
    float s = part[(b * 64 + lane) * 2 + 0];
    float q = part[(b * 64 + lane) * 2 + 1];
    for (int off = 32; off; off >>= 1) {
        s += __shfl_down(s, off, 64);
        q += __shfl_down(q, off, 64);
    }
    if (lane == 0) { stats[b * 2] = s; stats[b * 2 + 1] = q; }
}

// ---------------- norm + transpose: x[b][c][n] fp32 -> xn_t[b][n][c] bf16 ----------------
__global__ __launch_bounds__(256) void norm_t_kernel(
    const float* __restrict__ x, const float* __restrict__ gamma,
    const float* __restrict__ beta, const float* __restrict__ stats,
    ushort* __restrict__ xn_t)
{
    int b = blockIdx.z;
    float mean = stats[b * 2] * (1.0f / (float)CNT);
    float var = stats[b * 2 + 1] * (1.0f / (float)CNT) - mean * mean;
    float rinv = rsqrtf(var + 1e-5f);
    int n0 = blockIdx.x * 32, c0 = blockIdx.y * 32;
    __shared__ float tl[32][33];
    int tr = threadIdx.x >> 3;
    int tc4 = (threadIdx.x & 7) * 4;
    int c = c0 + tr;
    float gsc = gamma[c] * rinv;
    float bsc = beta[c] - mean * gsc;
    f32x4 v = *(const f32x4*)(x + ((b * CC + c) * NN + n0 + tc4));
    tl[tr][tc4 + 0] = v.x * gsc + bsc;
    tl[tr][tc4 + 1] = v.y * gsc + bsc;
    tl[tr][tc4 + 2] = v.z * gsc + bsc;
    tl[tr][tc4 + 3] = v.w * gsc + bsc;
    __syncthreads();
    int nr = threadIdx.x >> 3;
    int cg4 = (threadIdx.x & 7) * 4;
    ushort4 o;
    o.x = f2bf(tl[cg4 + 0][nr]);
    o.y = f2bf(tl[cg4 + 1][nr]);
    o.z = f2bf(tl[cg4 + 2][nr]);
    o.w = f2bf(tl[cg4 + 3][nr]);
    *(ushort4*)(xn_t + ((size_t)(b * NN + n0 + nr) * CC + c0 + cg4)) = o;
}

// ---------------- QKV GEMM: [768,256]x[256,4096] per batch, bf16 MFMA ----------------
// Q rows are PRE-SCALED by 2^-4 (= C^-0.5) so flash needs no scale.
__global__ __launch_bounds__(256) void qkv_kernel(
    const ushort* __restrict__ xn_t, const float* __restrict__ qkv_w,
    const float* __restrict__ qkv_b, ushort* __restrict__ q_t,
    ushort* __restrict__ k_t, ushort* __restrict__ v_g)
{
    int b = blockIdx.z;
    int d0 = blockIdx.x * 64;
    int i0 = blockIdx.y * 64;
    int t = threadIdx.x, w = t >> 6, l = t & 63, l15 = l & 15, g = l >> 4;
    __shared__ ushort b_lds[64 * 256];

    #pragma unroll
    for (int it = 0; it < 8; it++) {
        int cid = it * 256 + t;
        int rr = cid >> 5, cc = cid & 31;
        bf16x8 vv = *(const bf16x8*)(xn_t + ((size_t)(b * NN + i0 + rr) * CC + cc * 8));
        *(bf16x8*)(b_lds + rr * 256 + (cc ^ (rr & 7)) * 8) = vv;
    }
    bf16x8 af[8];
    int drow = d0 + w * 16 + l15;
    #pragma unroll
    for (int kk = 0; kk < 8; kk++) {
        const float* ap = qkv_w + drow * CC + kk * 32 + g * 8;
        f32x4 u0 = *(const f32x4*)ap;
        f32x4 u1 = *(const f32x4*)(ap + 4);
        bf16x8 a;
        a[0] = (short)f2bf(u0.x); a[1] = (short)f2bf(u0.y);
        a[2] = (short)f2bf(u0.z); a[3] = (short)f2bf(u0.w);
        a[4] = (short)f2bf(u1.x); a[5] = (short)f2bf(u1.y);
        a[6] = (short)f2bf(u1.z); a[7] = (short)f2bf(u1.w);
        af[kk] = a;
    }
    __syncthreads();

    f32x4 acc[4];
    #pragma unroll
    for (int it = 0; it < 4; it++) { f32x4 z = {0.f, 0.f, 0.f, 0.f}; acc[it] = z; }
    #pragma unroll
    for (int kk = 0; kk < 8; kk++) {
        int cc = kk * 4 + g;
        #pragma unroll
        for (int it = 0; it < 4; it++) {
            int il = it * 16 + l15;
            bf16x8 bf = *(const bf16x8*)(b_lds + il * 256 + (cc ^ (il & 7)) * 8);
            MFMA16(acc[it], af[kk], bf);
        }
    }
    int dbase = d0 + w * 16 + g * 4;
    f32x4 bias = *(const f32x4*)(qkv_b + dbase);
    float qs = (d0 < 256) ? 0.0625f : 1.0f;
    #pragma unroll
    for (int it = 0; it < 4; it++) {
        int i = i0 + it * 16 + l15;
        if (d0 < 512) {
            ushort4 o;
            o.x = f2bf((acc[it][0] + bias[0]) * qs);
            o.y = f2bf((acc[it][1] + bias[1]) * qs);
            o.z = f2bf((acc[it][2] + bias[2]) * qs);
            o.w = f2bf((acc[it][3] + bias[3]) * qs);
            ushort* dst = (d0 < 256) ? q_t : k_t;
            int dl = dbase - ((d0 < 256) ? 0 : 256);
            *(ushort4*)(dst + ((size_t)(b * NN + i) * CC + dl)) = o;
        } else {
            #pragma unroll
            for (int e = 0; e < 4; e++)
                v_g[(size_t)(b * CC + (dbase - 512 + e)) * NN + i] = f2bf(acc[it][e] + bias[e]);
        }
    }
}

// ---------------- flash attention: 8-wave blocks, KVBLK=64, double-buffered LDS ----------------
// ONE barrier per 64-j tile. Staging writes overlap compute (different buffer).
template <bool PARTIAL>
__global__ __launch_bounds__(512, 2) void flash_kernel(
    const ushort* __restrict__ q_t, const ushort* __restrict__ k_t,
    const ushort* __restrict__ v_g, ushort* __restrict__ out_t,
    float* __restrict__ O_part, float* __restrict__ ml_part, int segn)
{
    int b = blockIdx.z;
    int seg = blockIdx.y;
    int i0 = blockIdx.x * 128;
    int jbase = seg * segn;
    int t = threadIdx.x;
    int w = t >> 6, l = t & 63, l15 = l & 15, g = l >> 4;

    __shared__ ushort k_lds[2][64 * 256];   // [j][c] chunks XOR (j&7)
    __shared__ ushort v_lds[2][256 * 64];   // [c][j] chunks XOR (c&7)
    __shared__ ushort p_lds[128 * 64];      // [i][j] chunks XOR (i&7)

    bf16x8 qf[8];
    size_t qrow = (size_t)(b * NN + i0 + w * 16 + l15) * CC + g * 8;
    #pragma unroll
    for (int kk = 0; kk < 8; kk++) qf[kk] = *(const bf16x8*)(q_t + qrow + kk * 32);

    f32x4 O[16];
    #pragma unroll
    for (int tc = 0; tc < 16; tc++) { f32x4 z = {0.f, 0.f, 0.f, 0.f}; O[tc] = z; }
    float m_r[4], l_r[4];
    #pragma unroll
    for (int e = 0; e < 4; e++) { m_r[e] = -1e30f; l_r[e] = 0.f; }

    const ushort* kb = k_t + (size_t)b * NN * CC;
    const ushort* vb = v_g + (size_t)b * CC * NN;

    // prologue: tile 0 -> regs -> buf0
    bf16x8 kr[4], vr[4];
    #pragma unroll
    for (int it = 0; it < 4; it++) {
        int cid = it * 512 + t;
        kr[it] = *(const bf16x8*)(kb + (size_t)(jbase + (cid >> 5)) * CC + (cid & 31) * 8);
        vr[it] = *(const bf16x8*)(vb + (size_t)(cid >> 3) * NN + jbase + (cid & 7) * 8);
    }
    #pragma unroll
    for (int it = 0; it < 4; it++) {
        int cid = it * 512 + t;
        int jr = cid >> 5, cc = cid & 31;
        *(bf16x8*)(&k_lds[0][jr * 256 + (cc ^ (jr & 7)) * 8]) = kr[it];
        int cr = cid >> 3, cv = cid & 7;
        *(bf16x8*)(&v_lds[0][cr * 64 + (cv ^ (cr & 7)) * 8]) = vr[it];
    }
    __syncthreads();

    int cur = 0;
    for (int jj = 0; jj < segn; jj += 64) {
        bool more = (jj + 64 < segn);
        // issue next-tile global loads early (latency hides under compute)
        if (more) {
            #pragma unroll
            for (int it = 0; it < 4; it++) {
                int cid = it * 512 + t;
                kr[it] = *(const bf16x8*)(kb + (size_t)(jbase + jj + 64 + (cid >> 5)) * CC + (cid & 31) * 8);
                vr[it] = *(const bf16x8*)(vb + (size_t)(cid >> 3) * NN + jbase + jj + 64 + (cid & 7) * 8);
            }
        }
        const ushort* kl = k_lds[cur];
        const ushort* vl = v_lds[cur];

        // S = Q K^T  (4 independent accumulator chains)
        f32x4 sj[4];
        #pragma unroll
        for (int jg = 0; jg < 4; jg++) { f32x4 z = {0.f, 0.f, 0.f, 0.f}; sj[jg] = z; }
        __builtin_amdgcn_s_setprio(1);
        #pragma unroll
        for (int kk = 0; kk < 8; kk++) {
            int cc = kk * 4 + g;
            #pragma unroll
            for (int jg = 0; jg < 4; jg++) {
                int j = jg * 16 + l15;
                bf16x8 bk = *(const bf16x8*)(kl + j * 256 + ((cc ^ (j & 7)) * 8));
                MFMA16(sj[jg], qf[kk], bk);
            }
        }
        __builtin_amdgcn_s_setprio(0);

        // softmax, common path cross-lane-free (deferred max + deferred l-reduce)
        float mxl[4];
        bool need = false;
        #pragma unroll
        for (int e = 0; e < 4; e++) {
            mxl[e] = fmaxf(fmaxf(sj[0][e], sj[1][e]), fmaxf(sj[2][e], sj[3][e]));
            need = need || (mxl[e] > m_r[e] + 8.0f);
        }
        if (__any(need)) {
            #pragma unroll
            for (int e = 0; e < 4; e++) {
                float mx = mxl[e];
                mx = fmaxf(mx, __shfl_xor(mx, 1, 64));
                mx = fmaxf(mx, __shfl_xor(mx, 2, 64));
                mx = fmaxf(mx, __shfl_xor(mx, 4, 64));
                mx = fmaxf(mx, __shfl_xor(mx, 8, 64));
                if (mx > m_r[e]) {
                    float fac = __expf(m_r[e] - mx);
                    l_r[e] *= fac;
                    #pragma unroll
                    for (int tc = 0; tc < 16; tc++) O[tc][e] *= fac;
                    m_r[e] = mx;
                }
            }
        }
        float pv[4][4];  // [jg][e]
        #pragma unroll
        for (int jg = 0; jg < 4; jg++) {
            #pragma unroll
            for (int e = 0; e < 4; e++) {
                float p = __expf(sj[jg][e] - m_r[e]);
                l_r[e] += p;
                pv[jg][e] = p;
            }
        }

        // write P to LDS (wave-private rows), read back as A-fragments
        #pragma unroll
        for (int e = 0; e < 4; e++) {
            int ir = w * 16 + g * 4 + e;
            #pragma unroll
            for (int jg = 0; jg < 4; jg++) {
                int j = jg * 16 + l15;
                p_lds[ir * 64 + (((j >> 3) ^ (ir & 7)) * 8) + (j & 7)] = f2bf(pv[jg][e]);
            }
        }
        int ip = w * 16 + l15;
        bf16x8 pa0 = *(const bf16x8*)(p_lds + ip * 64 + ((g ^ (ip & 7)) * 8));
        bf16x8 pa1 = *(const bf16x8*)(p_lds + ip * 64 + (((4 + g) ^ (ip & 7)) * 8));

        // O += P V^T
        __builtin_amdgcn_s_setprio(1);
        #pragma unroll
        for (int tc = 0; tc < 16; tc++) {
            int c = tc * 16 + l15;
            bf16x8 v0 = *(const bf16x8*)(vl + c * 64 + ((g ^ (c & 7)) * 8));
            MFMA16(O[tc], pa0, v0);
            bf16x8 v1 = *(const bf16x8*)(vl + c * 64 + (((4 + g) ^ (c & 7)) * 8));
            MFMA16(O[tc], pa1, v1);
        }
        __builtin_amdgcn_s_setprio(0);

        // stage next tile into the other buffer (overlaps other waves' compute)
        if (more) {
            #pragma unroll
            for (int it = 0; it < 4; it++) {
                int cid = it * 512 + t;
                int jr = cid >> 5, cc = cid & 31;
                *(bf16x8*)(&k_lds[cur ^ 1][jr * 256 + (cc ^ (jr & 7)) * 8]) = kr[it];
                int cr = cid >> 3, cv = cid & 7;
                *(bf16x8*)(&v_lds[cur ^ 1][cr * 64 + (cv ^ (cr & 7)) * 8]) = vr[it];
            }
        }
        __syncthreads();
        cur ^= 1;
    }

    // epilogue: reduce deferred l across the 16-lane group
    #pragma unroll
    for (int e = 0; e < 4; e++) {
        float rs = l_r[e];
        rs += __shfl_xor(rs, 1, 64);
        rs += __shfl_xor(rs, 2, 64);
        rs += __shfl_xor(rs, 4, 64);
        rs += __shfl_xor(rs, 8, 64);
        l_r[e] = rs;
    }

    if (PARTIAL) {
        size_t obase = ((size_t)(seg * BB + b) * NN);
        #pragma unroll
        for (int e = 0; e < 4; e++) {
            int ir = i0 + w * 16 + g * 4 + e;
            float* orow = O_part + (obase + ir) * CC;
            #pragma unroll
            for (int tc = 0; tc < 16; tc++)
                orow[tc * 16 + l15] = O[tc][e];
            if (l15 == 0) {
                ml_part[(obase + ir) * 2 + 0] = m_r[e];
                ml_part[(obase + ir) * 2 + 1] = l_r[e];
            }
        }
    } else {
        #pragma unroll
        for (int e = 0; e < 4; e++) {
            float inv = 1.0f / fmaxf(l_r[e], 1e-20f);
            int ir = i0 + w * 16 + g * 4 + e;
            #pragma unroll
            for (int tc = 0; tc < 16; tc++)
                out_t[(size_t)(b * NN + ir) * CC + tc * 16 + l15] = f2bf(O[tc][e] * inv);
        }
    }
}

// ---------------- merge partial segments -> out_t bf16 ----------------
__global__ __launch_bounds__(256) void merge_kernel(
    const float* __restrict__ O_part, const float* __restrict__ ml_part,
    ushort* __restrict__ out_t, int S)
{
    int b = blockIdx.y;
    int t = threadIdx.x;
    int i = blockIdx.x * 64 + (t >> 2);
    int c0 = (t & 3) * 64;

    float w_s[4];
    float mstar = -1e30f;
    for (int s = 0; s < S; s++)
        mstar = fmaxf(mstar, ml_part[((size_t)(s * BB + b) * NN + i) * 2 + 0]);
    float lsum = 0.f;
    for (int s = 0; s < S; s++) {
        size_t mo = ((size_t)(s * BB + b) * NN + i) * 2;
        float wv = __expf(ml_part[mo] - mstar);
        lsum += ml_part[mo + 1] * wv;
        w_s[s] = wv;
    }
    float inv = 1.0f / fmaxf(lsum, 1e-20f);

    #pragma unroll 4
    for (int k = 0; k < 16; k++) {
        f32x4 acc = {0.f, 0.f, 0.f, 0.f};
        for (int s = 0; s < S; s++) {
            const float* op = O_part + ((size_t)(s * BB + b) * NN + i) * CC + c0 + k * 4;
            f32x4 v = *(const f32x4*)op;
            acc.x += v.x * w_s[s];
            acc.y += v.y * w_s[s];
            acc.z += v.z * w_s[s];
            acc.w += v.w * w_s[s];
        }
        ushort4 o;
        o.x = f2bf(acc.x * inv);
        o.y = f2bf(acc.y * inv);
        o.z = f2bf(acc.z * inv);
        o.w = f2bf(acc.w * inv);
        *(ushort4*)(out_t + (size_t)(b * NN + i) * CC + c0 + k * 4) = o;
    }
}

// ---------------- proj GEMM + bias + residual ----------------
__global__ __launch_bounds__(256) void proj_kernel(
    const ushort* __restrict__ out_t, const float* __restrict__ proj_w,
    const float* __restrict__ proj_b, const float* __restrict__ x,
    float* __restrict__ out)
{
    int b = blockIdx.z;
    int d0 = blockIdx.x * 64;
    int i0 = blockIdx.y * 256;
    int t = threadIdx.x, w = t >> 6, l = t & 63, l15 = l & 15, g = l >> 4;
    __shared__ ushort a_lds[64 * 256];

    #pragma unroll
    for (int it = 0; it < 8; it++) {
        int cid = it * 256 + t;
        int dd = cid >> 5, cc = cid & 31;
        const float* ap = proj_w + (d0 + dd) * CC + cc * 8;
        f32x4 u0 = *(const f32x4*)ap;
        f32x4 u1 = *(const f32x4*)(ap + 4);
        bf16x8 a;
        a[0] = (short)f2bf(u0.x); a[1] = (short)f2bf(u0.y);
        a[2] = (short)f2bf(u0.z); a[3] = (short)f2bf(u0.w);
        a[4] = (short)f2bf(u1.x); a[5] = (short)f2bf(u1.y);
        a[6] = (short)f2bf(u1.z); a[7] = (short)f2bf(u1.w);
        *(bf16x8*)(a_lds + dd * 256 + (cc ^ (dd & 7)) * 8) = a;
    }
    __syncthreads();

    f32x4 acc[16];
    #pragma unroll
    for (int it = 0; it < 16; it++) { f32x4 z = {0.f, 0.f, 0.f, 0.f}; acc[it] = z; }
    int dl = w * 16 + l15;
    #pragma unroll
    for (int kk = 0; kk < 8; kk++) {
        int cc = kk * 4 + g;
        bf16x8 af = *(const bf16x8*)(a_lds + dl * 256 + (cc ^ (dl & 7)) * 8);
        #pragma unroll
        for (int it = 0; it < 16; it++) {
            bf16x8 bfr = *(const bf16x8*)(out_t + (size_t)(b * NN + i0 + it * 16 + l15) * CC + kk * 32 + g * 8);
            MFMA16(acc[it], af, bfr);
        }
    }
    int dbase = d0 + w * 16 + g * 4;
    f32x4 pb = *(const f32x4*)(proj_b + dbase);
    #pragma unroll
    for (int it = 0; it < 16; it++) {
        int i = i0 + it * 16 + l15;
        #pragma unroll
        for (int e = 0; e < 4; e++) {
            int off = (b * CC + dbase + e) * NN + i;
            out[off] = acc[it][e] + pb[e] + x[off];
        }
    }
}

extern "C" void kernel_launch(void* const* d_in, const int* in_sizes, int n_in,
                              void* d_out, int out_size, void* d_ws, size_t ws_size,
                              hipStream_t stream) {
    const float* x      = (const float*)d_in[0];
    const float* gamma  = (const float*)d_in[1];
    const float* beta   = (const float*)d_in[2];
    const float* qkv_w  = (const float*)d_in[3];
    const float* qkv_b  = (const float*)d_in[4];
    const float* proj_w = (const float*)d_in[5];
    const float* proj_b = (const float*)d_in[6];
    float* out = (float*)d_out;

    char* ws = (char*)d_ws;
    float* part   = (float*)ws;
    float* stats  = (float*)(ws + 2048);
    ushort* xn_t  = (ushort*)(ws + 4096);
    ushort* q_t   = (ushort*)(ws + 4096 + 1ull * 8388608);
    ushort* k_t   = (ushort*)(ws + 4096 + 2ull * 8388608);
    ushort* v_g   = (ushort*)(ws + 4096 + 3ull * 8388608);
    ushort* out_t = xn_t;

    size_t mlbase = 4096 + 4ull * 8388608;            // 32 MB + 4 KB
    float* ml_part = (float*)(ws + mlbase);           // up to 512 KB
    size_t obase  = mlbase + 1048576;
    float* O_part = (float*)(ws + obase);             // S * 16 MB

    int S = 0;
    if (ws_size >= obase + 2ull * 16777216) S = 2;    // 32 i-blocks * S * 4 = 256 blocks

    stats_part<<<dim3(64, 4), 256, 0, stream>>>(x, part);
    stats_final<<<1, 256, 0, stream>>>(part, stats);
    norm_t_kernel<<<dim3(128, 8, 4), 256, 0, stream>>>(x, gamma, beta, stats, xn_t);
    qkv_kernel<<<dim3(12, 64, 4), 256, 0, stream>>>(xn_t, qkv_w, qkv_b, q_t, k_t, v_g);
    if (S > 0) {
        flash_kernel<true><<<dim3(32, S, 4), 512, 0, stream>>>(
            q_t, k_t, v_g, out_t, O_part, ml_part, NN / S);
        merge_kernel<<<dim3(64, 4), 256, 0, stream>>>(O_part, ml_part, out_t, S);
    } else {
        flash_kernel<false><<<dim3(32, 1, 4), 512, 0, stream>>>(
            q_t, k_t, v_g, out_t, nullptr, nullptr, NN);
    }
    proj_kernel<<<dim3(4, 16, 4), 256, 0, stream>>>(out_t, proj_w, proj_b, x, out);
}